// Round 1
// baseline (88.993 us; speedup 1.0000x reference)
//
#include <hip/hip_runtime.h>

#define BB 8            // batches
#define NN 8192         // points per set
#define DD 3
#define BLOCK 256
#define QPT 8                    // queries per thread
#define QPB (BLOCK * QPT)        // 2048 queries per block
#define QB (NN / QPB)            // 4 query-blocks per (dir, b)
#define TQ (2 * BB * NN)         // 131072 total queries

// K1: for its (dir, batch, query-block, ref-chunk) compute per-query partial
// min of (xx + yy - 2*x.y) over the chunk's refs. Refs staged in LDS as
// float4(-2y0, -2y1, -2y2, yy) -> inner loop is 3 FMA + 1 min per pair.
template <int CHUNK>
__global__ __launch_bounds__(BLOCK) void chamfer_partial(
    const float* __restrict__ preds, const float* __restrict__ gts,
    float* __restrict__ partial, int R) {
  __shared__ float4 lref[CHUNK];

  int bi = blockIdx.x;
  int r = bi % R;
  int qb = (bi / R) % QB;
  int b = (bi / (R * QB)) % BB;
  int dir = bi / (R * QB * BB);

  // dir 0: queries = preds, refs = gts  (loss_1: per-pred nearest gt)
  // dir 1: queries = gts, refs = preds  (loss_2: per-gt nearest pred)
  const float* qry = (dir == 0) ? preds : gts;
  const float* ref = (dir == 0) ? gts : preds;

  // ---- stage ref chunk into LDS ----
  const float* rbase = ref + ((size_t)b * NN + (size_t)r * CHUNK) * DD;
  for (int j = threadIdx.x; j < CHUNK; j += BLOCK) {
    float y0 = rbase[j * 3 + 0];
    float y1 = rbase[j * 3 + 1];
    float y2 = rbase[j * 3 + 2];
    lref[j] = make_float4(-2.f * y0, -2.f * y1, -2.f * y2,
                          y0 * y0 + y1 * y1 + y2 * y2);
  }
  __syncthreads();

  // ---- load this thread's 8 query points (96 contiguous bytes) ----
  int q0 = qb * QPB + threadIdx.x * QPT;
  const float* qbase = qry + ((size_t)b * NN + q0) * DD;
  float x0[QPT], x1[QPT], x2[QPT], xx[QPT], mn[QPT];
#pragma unroll
  for (int k = 0; k < QPT; ++k) {
    x0[k] = qbase[k * 3 + 0];
    x1[k] = qbase[k * 3 + 1];
    x2[k] = qbase[k * 3 + 2];
    xx[k] = x0[k] * x0[k] + x1[k] * x1[k] + x2[k] * x2[k];
    mn[k] = 3.4e38f;
  }

  // ---- inner loop: 4 VALU per pair ----
#pragma unroll 4
  for (int j = 0; j < CHUNK; ++j) {
    float4 rv = lref[j];  // broadcast read, conflict-free
#pragma unroll
    for (int k = 0; k < QPT; ++k) {
      float t = fmaf(x0[k], rv.x, fmaf(x1[k], rv.y, fmaf(x2[k], rv.z, rv.w)));
      mn[k] = fminf(mn[k], t);
    }
  }

  // ---- write partial mins (xx folded in; constant across R so min-safe) ----
  size_t gq = ((size_t)dir * BB + b) * NN + q0;
  float* out = partial + (size_t)r * TQ + gq;
#pragma unroll
  for (int k = 0; k < QPT; ++k) out[k] = mn[k] + xx[k];
}

// K2: per query, min over R slices; deterministic block-tree sum.
__global__ __launch_bounds__(BLOCK) void chamfer_reduce(
    const float* __restrict__ partial, float* __restrict__ bsums, int R) {
  int q = blockIdx.x * BLOCK + threadIdx.x;
  float m = 3.4e38f;
  for (int r = 0; r < R; ++r) m = fminf(m, partial[(size_t)r * TQ + q]);
  __shared__ float s[BLOCK];
  s[threadIdx.x] = m;
  __syncthreads();
  for (int o = BLOCK / 2; o > 0; o >>= 1) {
    if (threadIdx.x < o) s[threadIdx.x] += s[threadIdx.x + o];
    __syncthreads();
  }
  if (threadIdx.x == 0) bsums[blockIdx.x] = s[0];
}

// K3: deterministic single-block final sum.
__global__ __launch_bounds__(BLOCK) void chamfer_final(
    const float* __restrict__ bsums, float* __restrict__ out, int n) {
  float v = 0.f;
  for (int i = threadIdx.x; i < n; i += BLOCK) v += bsums[i];
  __shared__ float s[BLOCK];
  s[threadIdx.x] = v;
  __syncthreads();
  for (int o = BLOCK / 2; o > 0; o >>= 1) {
    if (threadIdx.x < o) s[threadIdx.x] += s[threadIdx.x + o];
    __syncthreads();
  }
  if (threadIdx.x == 0) out[0] = s[0];
}

extern "C" void kernel_launch(void* const* d_in, const int* in_sizes, int n_in,
                              void* d_out, int out_size, void* d_ws,
                              size_t ws_size, hipStream_t stream) {
  const float* preds = (const float*)d_in[0];
  const float* gts = (const float*)d_in[1];
  float* out = (float*)d_out;
  float* partial = (float*)d_ws;

  // pick R (ref-chunk split) by available workspace: need R*TQ*4 + bsums
  int R;
  size_t need16 = (size_t)16 * TQ * 4 + 4096;
  size_t need8 = (size_t)8 * TQ * 4 + 4096;
  size_t need4 = (size_t)4 * TQ * 4 + 4096;
  if (ws_size >= need16)
    R = 16;
  else if (ws_size >= need8)
    R = 8;
  else if (ws_size >= need4)
    R = 4;
  else
    R = 2;

  float* bsums = partial + (size_t)R * TQ;
  int nq_blocks = TQ / BLOCK;  // 512

  int grid1 = 2 * BB * QB * R;
  switch (R) {
    case 16:
      chamfer_partial<NN / 16><<<grid1, BLOCK, 0, stream>>>(preds, gts, partial, R);
      break;
    case 8:
      chamfer_partial<NN / 8><<<grid1, BLOCK, 0, stream>>>(preds, gts, partial, R);
      break;
    case 4:
      chamfer_partial<NN / 4><<<grid1, BLOCK, 0, stream>>>(preds, gts, partial, R);
      break;
    default:
      chamfer_partial<NN / 2><<<grid1, BLOCK, 0, stream>>>(preds, gts, partial, R);
      break;
  }
  chamfer_reduce<<<nq_blocks, BLOCK, 0, stream>>>(partial, bsums, R);
  chamfer_final<<<1, BLOCK, 0, stream>>>(bsums, out, nq_blocks);
}